// Round 1
// baseline (2579.037 us; speedup 1.0000x reference)
//
#include <hip/hip_runtime.h>
#include <math.h>

#define Bb 2
#define Ss 2048
#define Dd 1024
#define Hh 16
#define HD 64
#define Mm (Bb*Ss)   // 4096 rows total

// ---------------------------------------------------------------------------
// Tiled fp32 GEMM: out = X(M,K) @ W(K,N) + bias
// MODE 0: scatter output to [B,H,S,hd]  (QKV projections)
// MODE 1: row-major [M,N] with ReLU      (output projection)
// 64x64 tile, 256 threads, 4x4 per thread, K-tile 16.
// ---------------------------------------------------------------------------
template<int MODE>
__global__ __launch_bounds__(256)
void gemm_bias(const float* __restrict__ X, const float* __restrict__ W,
               const float* __restrict__ bias, float* __restrict__ out,
               int M, int N, int K)
{
    __shared__ float As[64][17];   // +1 pad: tm-stride 68 -> 2-way (free)
    __shared__ float Bs[16][65];   // +1 pad

    const int tid = threadIdx.x;
    const int tm = tid >> 4;       // 0..15
    const int tn = tid & 15;       // 0..15
    const int row0 = blockIdx.y * 64;
    const int col0 = blockIdx.x * 64;

    float acc[4][4] = {};

    for (int k0 = 0; k0 < K; k0 += 16) {
        {   // load A tile 64x16 (one float4 per thread)
            int r = tid >> 2, c = (tid & 3) << 2;
            const float4 v = *(const float4*)&X[(size_t)(row0 + r)*K + k0 + c];
            As[r][c] = v.x; As[r][c+1] = v.y; As[r][c+2] = v.z; As[r][c+3] = v.w;
        }
        {   // load B tile 16x64 (one float4 per thread)
            int r = tid >> 4, c = (tid & 15) << 2;
            const float4 v = *(const float4*)&W[(size_t)(k0 + r)*N + col0 + c];
            Bs[r][c] = v.x; Bs[r][c+1] = v.y; Bs[r][c+2] = v.z; Bs[r][c+3] = v.w;
        }
        __syncthreads();
        #pragma unroll
        for (int kk = 0; kk < 16; ++kk) {
            float a[4], b[4];
            #pragma unroll
            for (int i = 0; i < 4; ++i) a[i] = As[tm*4+i][kk];
            #pragma unroll
            for (int j = 0; j < 4; ++j) b[j] = Bs[kk][tn*4+j];
            #pragma unroll
            for (int i = 0; i < 4; ++i)
                #pragma unroll
                for (int j = 0; j < 4; ++j)
                    acc[i][j] = fmaf(a[i], b[j], acc[i][j]);
        }
        __syncthreads();
    }

    #pragma unroll
    for (int i = 0; i < 4; ++i) {
        const int m = row0 + tm*4 + i;
        #pragma unroll
        for (int j = 0; j < 4; ++j) {
            const int n = col0 + tn*4 + j;
            float v = acc[i][j] + bias[n];
            if (MODE == 1) {
                v = fmaxf(v, 0.0f);
                out[(size_t)m*N + n] = v;
            } else {
                const int b_ = m / Ss, s_ = m % Ss;
                const int h_ = n >> 6, e_ = n & 63;
                out[((size_t)(b_*Hh + h_)*Ss + s_)*HD + e_] = v;
            }
        }
    }
}

// ---------------------------------------------------------------------------
// Flash-style attention, fp32. Q,K,V in [B,H,S,hd]; O written [B,S,D].
// Block: 256 threads handles 16 queries for one (b,h). One pass over K/V in
// tiles of 256 keys; online softmax (m,l per query in LDS); accumulator in
// registers per (query, 4-dim slice).
// ---------------------------------------------------------------------------
__global__ __launch_bounds__(256)
void attention(const float* __restrict__ Q, const float* __restrict__ K,
               const float* __restrict__ V, float* __restrict__ O)
{
    const int b  = blockIdx.z;
    const int h  = blockIdx.y;
    const int q0 = blockIdx.x * 16;
    const size_t base = ((size_t)(b*Hh + h)) * Ss * HD;
    const float* Kb = K + base;
    const float* Vb = V + base;

    __shared__ float Qs[16][68];      // padded; rows 16B-aligned (68*4=272)
    __shared__ float Pt[16][257];     // exp'd scores for current 256-key tile
    __shared__ float red[16][17];
    __shared__ float m_sh[16], l_sh[16], alpha_sh[16];

    const int t = threadIdx.x;

    {   // load + pre-scale Q tile (1/sqrt(64) = 0.125)
        int q = t >> 4, c = (t & 15) << 2;
        const float4 v = *(const float4*)&Q[base + (size_t)(q0 + q)*HD + c];
        Qs[q][c]   = v.x * 0.125f;
        Qs[q][c+1] = v.y * 0.125f;
        Qs[q][c+2] = v.z * 0.125f;
        Qs[q][c+3] = v.w * 0.125f;
    }
    if (t < 16) { m_sh[t] = -1e30f; l_sh[t] = 0.0f; }
    __syncthreads();

    const int q  = t & 15;        // score-phase query
    const int jg = t >> 4;        // score-phase key group (0..15)
    const int qo = t >> 4;        // accum-phase query
    const int e4 = (t & 15) << 2; // accum-phase dim slice

    float4 acc = make_float4(0.f, 0.f, 0.f, 0.f);
    float sreg[16];

    for (int tile = 0; tile < Ss; tile += 256) {
        // (a) raw scores: 16 keys per thread, local max
        float lmax = -1e30f;
        const float4* qv = (const float4*)&Qs[q][0];
        #pragma unroll
        for (int jj = 0; jj < 16; ++jj) {
            const int jl = jg + (jj << 4);
            const float4* kr = (const float4*)&Kb[(size_t)(tile + jl)*HD];
            float s = 0.f;
            #pragma unroll
            for (int e = 0; e < HD/4; ++e) {
                const float4 kv = kr[e];
                const float4 qq = qv[e];
                s = fmaf(qq.x, kv.x, s);
                s = fmaf(qq.y, kv.y, s);
                s = fmaf(qq.z, kv.z, s);
                s = fmaf(qq.w, kv.w, s);
            }
            sreg[jj] = s;
            lmax = fmaxf(lmax, s);
        }
        red[q][jg] = lmax;
        __syncthreads();
        if (t < 16) {   // new running max + rescale factor
            const float m_old = m_sh[t];
            float mt = m_old;
            #pragma unroll
            for (int i = 0; i < 16; ++i) mt = fmaxf(mt, red[t][i]);
            m_sh[t] = mt;
            alpha_sh[t] = __expf(m_old - mt);
        }
        __syncthreads();
        // (b) exponentiate + partial sums
        {
            const float mq = m_sh[q];
            float lsum = 0.f;
            #pragma unroll
            for (int jj = 0; jj < 16; ++jj) {
                const int jl = jg + (jj << 4);
                const float p = __expf(sreg[jj] - mq);
                Pt[q][jl] = p;
                lsum += p;
            }
            red[q][jg] = lsum;
        }
        __syncthreads();
        if (t < 16) {   // running denominator
            float s = 0.f;
            #pragma unroll
            for (int i = 0; i < 16; ++i) s += red[t][i];
            l_sh[t] = l_sh[t] * alpha_sh[t] + s;
        }
        // (c) rescale accumulator, accumulate P @ V for this tile
        {
            const float a_ = alpha_sh[qo];
            acc.x *= a_; acc.y *= a_; acc.z *= a_; acc.w *= a_;
            for (int jl = 0; jl < 256; ++jl) {
                const float p = Pt[qo][jl];
                const float4 v = *(const float4*)&Vb[(size_t)(tile + jl)*HD + e4];
                acc.x = fmaf(p, v.x, acc.x);
                acc.y = fmaf(p, v.y, acc.y);
                acc.z = fmaf(p, v.z, acc.z);
                acc.w = fmaf(p, v.w, acc.w);
            }
        }
        __syncthreads();   // protects Pt/m/alpha for next tile; flushes l_sh
    }

    const float inv = 1.0f / l_sh[qo];
    float4 o;
    o.x = acc.x * inv; o.y = acc.y * inv; o.z = acc.z * inv; o.w = acc.w * inv;
    // O in [B, S, D] layout (transpose back: D index = h*64 + e)
    *(float4*)&O[((size_t)(b*Ss) + q0 + qo)*Dd + h*HD + e4] = o;
}

// ---------------------------------------------------------------------------
// LayerNorm over last dim (1024), no affine. One block per row.
// ---------------------------------------------------------------------------
__global__ __launch_bounds__(256)
void layernorm(const float* __restrict__ X, float* __restrict__ out)
{
    const int row = blockIdx.x;
    const float4 v = ((const float4*)(X + (size_t)row*Dd))[threadIdx.x];
    float s  = v.x + v.y + v.z + v.w;
    float ss = v.x*v.x + v.y*v.y + v.z*v.z + v.w*v.w;
    #pragma unroll
    for (int off = 32; off > 0; off >>= 1) {
        s  += __shfl_down(s,  off);
        ss += __shfl_down(ss, off);
    }
    __shared__ float rs[4], rss[4];
    const int wid = threadIdx.x >> 6, lid = threadIdx.x & 63;
    if (lid == 0) { rs[wid] = s; rss[wid] = ss; }
    __syncthreads();
    s  = rs[0] + rs[1] + rs[2] + rs[3];
    ss = rss[0] + rss[1] + rss[2] + rss[3];
    const float mean = s * (1.0f / Dd);
    const float var  = ss * (1.0f / Dd) - mean * mean;
    const float rstd = rsqrtf(var + 1e-5f);
    float4 o;
    o.x = (v.x - mean) * rstd;
    o.y = (v.y - mean) * rstd;
    o.z = (v.z - mean) * rstd;
    o.w = (v.w - mean) * rstd;
    ((float4*)(out + (size_t)row*Dd))[threadIdx.x] = o;
}

// ---------------------------------------------------------------------------
extern "C" void kernel_launch(void* const* d_in, const int* in_sizes, int n_in,
                              void* d_out, int out_size, void* d_ws, size_t ws_size,
                              hipStream_t stream)
{
    const float* x  = (const float*)d_in[0];
    const float* Wq = (const float*)d_in[1];
    const float* bq = (const float*)d_in[2];
    const float* Wk = (const float*)d_in[3];
    const float* bk = (const float*)d_in[4];
    const float* Wv = (const float*)d_in[5];
    const float* bv = (const float*)d_in[6];
    const float* Wo = (const float*)d_in[7];
    const float* bo = (const float*)d_in[8];
    float* out = (float*)d_out;

    // workspace layout: Q | K | V | O  (4 x 16 MB = 64 MB)
    float* Qb = (float*)d_ws;
    float* Kb = Qb + (size_t)Mm*Dd;
    float* Vb = Kb + (size_t)Mm*Dd;
    float* Ob = Vb + (size_t)Mm*Dd;
    float* Rb = Qb;   // ReLU(proj) output reuses Q region (Q dead by then)

    const dim3 gg(Dd/64, Mm/64);
    const dim3 blk(256);
    gemm_bias<0><<<gg, blk, 0, stream>>>(x,  Wq, bq, Qb, Mm, Dd, Dd);
    gemm_bias<0><<<gg, blk, 0, stream>>>(x,  Wk, bk, Kb, Mm, Dd, Dd);
    gemm_bias<0><<<gg, blk, 0, stream>>>(x,  Wv, bv, Vb, Mm, Dd, Dd);
    attention<<<dim3(Ss/16, Hh, Bb), blk, 0, stream>>>(Qb, Kb, Vb, Ob);
    gemm_bias<1><<<gg, blk, 0, stream>>>(Ob, Wo, bo, Rb, Mm, Dd, Dd);
    layernorm<<<dim3(Mm), blk, 0, stream>>>(Rb, out);
}

// Round 2
// 1001.217 us; speedup vs baseline: 2.5759x; 2.5759x over previous
//
#include <hip/hip_runtime.h>
#include <hip/hip_bf16.h>
#include <math.h>

#define Bb 2
#define Ss 2048
#define Dd 1024
#define Hh 16
#define HD 64
#define Mm (Bb*Ss)   // 4096 rows total

typedef __attribute__((ext_vector_type(8))) short bf8_t;  // 8 bf16 (4 VGPRs)
typedef __attribute__((ext_vector_type(4))) float f4_t;   // 4 fp32

#define LOG2E 1.4426950408889634f

// ---------------------------------------------------------------------------
// Tiled fp32 GEMM: out = X(M,K) @ W(K,N) + bias
// MODE 0: bf16 out, scatter to [B,H,S,hd], scaled   (Q and K projections)
// MODE 2: bf16 out, scatter to [B,H,hd,S] (V^T)     (V projection)
// MODE 1: fp32 out, row-major [M,N] with ReLU       (output projection)
// ---------------------------------------------------------------------------
template<int MODE>
__global__ __launch_bounds__(256)
void gemm_bias(const float* __restrict__ X, const float* __restrict__ W,
               const float* __restrict__ bias, void* __restrict__ out_,
               int M, int N, int K, float scale)
{
    __shared__ float As[64][17];
    __shared__ float Bs[16][65];

    const int tid = threadIdx.x;
    const int tm = tid >> 4;
    const int tn = tid & 15;
    const int row0 = blockIdx.y * 64;
    const int col0 = blockIdx.x * 64;

    float acc[4][4] = {};

    for (int k0 = 0; k0 < K; k0 += 16) {
        {
            int r = tid >> 2, c = (tid & 3) << 2;
            const float4 v = *(const float4*)&X[(size_t)(row0 + r)*K + k0 + c];
            As[r][c] = v.x; As[r][c+1] = v.y; As[r][c+2] = v.z; As[r][c+3] = v.w;
        }
        {
            int r = tid >> 4, c = (tid & 15) << 2;
            const float4 v = *(const float4*)&W[(size_t)(k0 + r)*N + col0 + c];
            Bs[r][c] = v.x; Bs[r][c+1] = v.y; Bs[r][c+2] = v.z; Bs[r][c+3] = v.w;
        }
        __syncthreads();
        #pragma unroll
        for (int kk = 0; kk < 16; ++kk) {
            float a[4], b[4];
            #pragma unroll
            for (int i = 0; i < 4; ++i) a[i] = As[tm*4+i][kk];
            #pragma unroll
            for (int j = 0; j < 4; ++j) b[j] = Bs[kk][tn*4+j];
            #pragma unroll
            for (int i = 0; i < 4; ++i)
                #pragma unroll
                for (int j = 0; j < 4; ++j)
                    acc[i][j] = fmaf(a[i], b[j], acc[i][j]);
        }
        __syncthreads();
    }

    #pragma unroll
    for (int i = 0; i < 4; ++i) {
        const int m = row0 + tm*4 + i;
        const int b_ = m >> 11;           // m / Ss
        const int s_ = m & (Ss - 1);
        #pragma unroll
        for (int j = 0; j < 4; ++j) {
            const int n = col0 + tn*4 + j;
            float v = acc[i][j] + bias[n];
            if (MODE == 1) {
                float* out = (float*)out_;
                out[(size_t)m*N + n] = fmaxf(v, 0.0f);
            } else {
                const int h_ = n >> 6, e_ = n & 63;
                __hip_bfloat16* out = (__hip_bfloat16*)out_;
                const __hip_bfloat16 hv = __float2bfloat16(v * scale);
                if (MODE == 0)
                    out[((size_t)(b_*Hh + h_)*Ss + s_)*HD + e_] = hv;          // [B,H,S,hd]
                else
                    out[((size_t)(b_*Hh + h_)*HD + e_)*Ss + s_] = hv;          // [B,H,hd,S]
            }
        }
    }
}

// ---------------------------------------------------------------------------
// MFMA flash attention, bf16 inputs, fp32 accumulate. Per-wave independent:
// each wave owns 32 queries; iterates 64-key tiles. Q/K fragments read
// directly from global (b128, L1/L2-cached); V read from pre-transposed
// [B,H,hd,S]. P transits C-layout -> A-layout via per-wave XOR-swizzled LDS.
// No __syncthreads anywhere.
// ---------------------------------------------------------------------------
__device__ __forceinline__ float redmax16(float v) {
    v = fmaxf(v, __shfl_xor(v, 1));
    v = fmaxf(v, __shfl_xor(v, 2));
    v = fmaxf(v, __shfl_xor(v, 4));
    v = fmaxf(v, __shfl_xor(v, 8));
    return v;
}
__device__ __forceinline__ float redsum16(float v) {
    v += __shfl_xor(v, 1);
    v += __shfl_xor(v, 2);
    v += __shfl_xor(v, 4);
    v += __shfl_xor(v, 8);
    return v;
}

__global__ __launch_bounds__(256, 2)
void attn_mfma(const __hip_bfloat16* __restrict__ Qh,
               const __hip_bfloat16* __restrict__ Kh,
               const __hip_bfloat16* __restrict__ Vt,
               float* __restrict__ O)
{
    const int b    = blockIdx.z;
    const int h    = blockIdx.y;
    const int wave = threadIdx.x >> 6;
    const int lane = threadIdx.x & 63;
    const int llo  = lane & 15;
    const int lhi  = lane >> 4;
    const int qb   = blockIdx.x * 128 + wave * 32;

    const size_t base = ((size_t)(b*Hh + h)) * Ss * HD;   // same extent for Q/K/V^T
    const __hip_bfloat16* Kp = Kh + base;
    const __hip_bfloat16* Vp = Vt + base;

    __shared__ __hip_bfloat16 Pl[4][32*64];
    __hip_bfloat16* Pw = &Pl[wave][0];

    // Q A-fragments (A[m=llo][k=lhi*8+i]), pre-scaled by 1/8 in projection
    bf8_t qf[2][2];
    #pragma unroll
    for (int s = 0; s < 2; ++s)
        #pragma unroll
        for (int d = 0; d < 2; ++d)
            qf[s][d] = *(const bf8_t*)&Qh[base + (size_t)(qb + 16*s + llo)*HD + 32*d + lhi*8];

    f4_t o_[2][4];
    float mrow[2][4], lrow[2][4];
    #pragma unroll
    for (int s = 0; s < 2; ++s) {
        #pragma unroll
        for (int n = 0; n < 4; ++n) o_[s][n] = (f4_t){0.f,0.f,0.f,0.f};
        #pragma unroll
        for (int r = 0; r < 4; ++r) { mrow[s][r] = -1e30f; lrow[s][r] = 0.f; }
    }

    const f4_t zf = {0.f,0.f,0.f,0.f};
    const int llo7 = llo & 7;
    const int llo8 = llo >> 3;

    for (int k0 = 0; k0 < Ss; k0 += 64) {
        // ---- S = Q K^T (16 MFMAs) ----
        f4_t sacc[2][4];
        #pragma unroll
        for (int ks = 0; ks < 4; ++ks) {
            const __hip_bfloat16* kr = &Kp[(size_t)(k0 + 16*ks + llo)*HD + lhi*8];
            const bf8_t kf0 = *(const bf8_t*)kr;          // B[k=lhi*8+i][n=key]
            const bf8_t kf1 = *(const bf8_t*)(kr + 32);
            #pragma unroll
            for (int s = 0; s < 2; ++s) {
                sacc[s][ks] = __builtin_amdgcn_mfma_f32_16x16x32_bf16(qf[s][0], kf0, zf, 0, 0, 0);
                sacc[s][ks] = __builtin_amdgcn_mfma_f32_16x16x32_bf16(qf[s][1], kf1, sacc[s][ks], 0, 0, 0);
            }
        }

        // ---- online softmax + P -> LDS (bf16, A-layout target, XOR swizzle) ----
        float alpha[2][4];
        #pragma unroll
        for (int s = 0; s < 2; ++s) {
            #pragma unroll
            for (int r = 0; r < 4; ++r) {
                const float s0 = sacc[s][0][r], s1 = sacc[s][1][r];
                const float s2 = sacc[s][2][r], s3 = sacc[s][3][r];
                float mx = fmaxf(fmaxf(s0, s1), fmaxf(s2, s3));
                mx = redmax16(mx);
                const float nm = fmaxf(mrow[s][r], mx);
                alpha[s][r] = exp2f((mrow[s][r] - nm) * LOG2E);
                mrow[s][r] = nm;
                const float nb = -nm * LOG2E;
                const float p0 = exp2f(fmaf(s0, LOG2E, nb));
                const float p1 = exp2f(fmaf(s1, LOG2E, nb));
                const float p2 = exp2f(fmaf(s2, LOG2E, nb));
                const float p3 = exp2f(fmaf(s3, LOG2E, nb));
                const float sm = redsum16(p0 + p1 + p2 + p3);
                lrow[s][r] = fmaf(lrow[s][r], alpha[s][r], sm);
                // store: P[q][key], key-chunk (key>>3) XOR-swizzled by (q&7)
                const int q   = 16*s + 4*lhi + r;
                const int q7  = q & 7;
                const int ro  = q*64 + llo7;
                Pw[ro + (((llo8 + 0) ^ q7) << 3)] = __float2bfloat16(p0);
                Pw[ro + (((llo8 + 2) ^ q7) << 3)] = __float2bfloat16(p1);
                Pw[ro + (((llo8 + 4) ^ q7) << 3)] = __float2bfloat16(p2);
                Pw[ro + (((llo8 + 6) ^ q7) << 3)] = __float2bfloat16(p3);
            }
        }
        asm volatile("s_waitcnt lgkmcnt(0)" ::: "memory");

        // ---- rescale O by alpha ----
        #pragma unroll
        for (int s = 0; s < 2; ++s)
            #pragma unroll
            for (int n = 0; n < 4; ++n)
                #pragma unroll
                for (int r = 0; r < 4; ++r)
                    o_[s][n][r] *= alpha[s][r];

        // ---- O += P V (16 MFMAs) ----
        #pragma unroll
        for (int d = 0; d < 2; ++d) {
            bf8_t pf[2];
            #pragma unroll
            for (int s = 0; s < 2; ++s) {
                const int q = 16*s + llo;
                pf[s] = *(const bf8_t*)&Pw[q*64 + ((((d<<2) + lhi) ^ (q & 7)) << 3)];
            }
            #pragma unroll
            for (int n = 0; n < 4; ++n) {
                const bf8_t vf = *(const bf8_t*)&Vp[(size_t)(llo + 16*n)*Ss + k0 + 32*d + lhi*8];
                #pragma unroll
                for (int s = 0; s < 2; ++s)
                    o_[s][n] = __builtin_amdgcn_mfma_f32_16x16x32_bf16(pf[s], vf, o_[s][n], 0, 0, 0);
            }
        }
        asm volatile("" ::: "memory");   // keep next tile's P stores below these reads
    }

    // ---- epilogue: O[b, q, h*64 + hd] = o / l ----
    #pragma unroll
    for (int s = 0; s < 2; ++s) {
        #pragma unroll
        for (int r = 0; r < 4; ++r) {
            const float inv = 1.0f / lrow[s][r];
            const int q = qb + 16*s + 4*lhi + r;
            float* orow = &O[((size_t)(b*Ss) + q)*Dd + h*HD + llo];
            #pragma unroll
            for (int n = 0; n < 4; ++n)
                orow[16*n] = o_[s][n][r] * inv;
        }
    }
}

// ---------------------------------------------------------------------------
// LayerNorm over last dim (1024), no affine. One block per row.
// ---------------------------------------------------------------------------
__global__ __launch_bounds__(256)
void layernorm(const float* __restrict__ X, float* __restrict__ out)
{
    const int row = blockIdx.x;
    const float4 v = ((const float4*)(X + (size_t)row*Dd))[threadIdx.x];
    float s  = v.x + v.y + v.z + v.w;
    float ss = v.x*v.x + v.y*v.y + v.z*v.z + v.w*v.w;
    #pragma unroll
    for (int off = 32; off > 0; off >>= 1) {
        s  += __shfl_down(s,  off);
        ss += __shfl_down(ss, off);
    }
    __shared__ float rs[4], rss[4];
    const int wid = threadIdx.x >> 6, lid = threadIdx.x & 63;
    if (lid == 0) { rs[wid] = s; rss[wid] = ss; }
    __syncthreads();
    s  = rs[0] + rs[1] + rs[2] + rs[3];
    ss = rss[0] + rss[1] + rss[2] + rss[3];
    const float mean = s * (1.0f / Dd);
    const float var  = ss * (1.0f / Dd) - mean * mean;
    const float rstd = rsqrtf(var + 1e-5f);
    float4 o;
    o.x = (v.x - mean) * rstd;
    o.y = (v.y - mean) * rstd;
    o.z = (v.z - mean) * rstd;
    o.w = (v.w - mean) * rstd;
    ((float4*)(out + (size_t)row*Dd))[threadIdx.x] = o;
}

// ---------------------------------------------------------------------------
extern "C" void kernel_launch(void* const* d_in, const int* in_sizes, int n_in,
                              void* d_out, int out_size, void* d_ws, size_t ws_size,
                              hipStream_t stream)
{
    const float* x  = (const float*)d_in[0];
    const float* Wq = (const float*)d_in[1];
    const float* bq = (const float*)d_in[2];
    const float* Wk = (const float*)d_in[3];
    const float* bk = (const float*)d_in[4];
    const float* Wv = (const float*)d_in[5];
    const float* bv = (const float*)d_in[6];
    const float* Wo = (const float*)d_in[7];
    const float* bo = (const float*)d_in[8];
    float* out = (float*)d_out;

    // ws: Qh | Kh | Vt (bf16, 8MB each) | Ob | Rb (fp32, 16MB each) = 56MB
    __hip_bfloat16* Qh = (__hip_bfloat16*)d_ws;
    __hip_bfloat16* Kh = Qh + (size_t)Mm*Dd;
    __hip_bfloat16* Vt = Kh + (size_t)Mm*Dd;
    float* Ob = (float*)(Vt + (size_t)Mm*Dd);
    float* Rb = Ob + (size_t)Mm*Dd;

    const dim3 gg(Dd/64, Mm/64);
    const dim3 blk(256);
    gemm_bias<0><<<gg, blk, 0, stream>>>(x,  Wq, bq, Qh, Mm, Dd, Dd, 0.125f);
    gemm_bias<0><<<gg, blk, 0, stream>>>(x,  Wk, bk, Kh, Mm, Dd, Dd, 1.0f);
    gemm_bias<2><<<gg, blk, 0, stream>>>(x,  Wv, bv, Vt, Mm, Dd, Dd, 1.0f);
    attn_mfma<<<dim3(Ss/128, Hh, Bb), blk, 0, stream>>>(Qh, Kh, Vt, Ob);
    gemm_bias<1><<<gg, blk, 0, stream>>>(Ob, Wo, bo, Rb, Mm, Dd, Dd, 1.0f);
    layernorm<<<dim3(Mm), blk, 0, stream>>>(Rb, out);
}

// Round 3
// 372.677 us; speedup vs baseline: 6.9203x; 2.6866x over previous
//
#include <hip/hip_runtime.h>
#include <hip/hip_bf16.h>
#include <math.h>

#define Bb 2
#define Ss 2048
#define Dd 1024
#define Hh 16
#define HD 64
#define Mm (Bb*Ss)   // 4096 rows total

typedef __attribute__((ext_vector_type(8))) short bf8_t;  // 8 bf16 (4 VGPRs)
typedef __attribute__((ext_vector_type(4))) float f4_t;   // 4 fp32

#define LOG2E 1.4426950408889634f

#define AS1 __attribute__((address_space(1)))
#define AS3 __attribute__((address_space(3)))

__device__ __forceinline__ void gl2lds16(const void* g, void* l) {
    __builtin_amdgcn_global_load_lds((const AS1 unsigned int*)g,
                                     (AS3 unsigned int*)l, 16, 0, 0);
}
__device__ __forceinline__ short bfr(float f) {
    __hip_bfloat16 h = __float2bfloat16(f);
    return *reinterpret_cast<short*>(&h);
}

// ---------------------------------------------------------------------------
// cast x (fp32) -> bf16, 8 elems/thread
// ---------------------------------------------------------------------------
__global__ __launch_bounds__(256)
void cast_x(const float* __restrict__ x, __hip_bfloat16* __restrict__ xh)
{
    const size_t i = ((size_t)blockIdx.x * 256 + threadIdx.x) * 8;
    const float4 a = *(const float4*)&x[i];
    const float4 b = *(const float4*)&x[i + 4];
    bf8_t o;
    o[0] = bfr(a.x); o[1] = bfr(a.y); o[2] = bfr(a.z); o[3] = bfr(a.w);
    o[4] = bfr(b.x); o[5] = bfr(b.y); o[6] = bfr(b.z); o[7] = bfr(b.w);
    *(bf8_t*)&xh[i] = o;
}

// ---------------------------------------------------------------------------
// transpose + cast: Wt[n][k] = bf16(W[k][n]),  1024x1024, 32x32 LDS tiles
// ---------------------------------------------------------------------------
__global__ __launch_bounds__(256)
void tcast(const float* __restrict__ W, __hip_bfloat16* __restrict__ Wt)
{
    __shared__ float t[32][33];
    const int n0 = blockIdx.x * 32, k0 = blockIdx.y * 32;
    const int tx = threadIdx.x & 31, ty = threadIdx.x >> 5;   // ty 0..7
    #pragma unroll
    for (int rr = 0; rr < 4; ++rr)
        t[ty + rr*8][tx] = W[(size_t)(k0 + ty + rr*8) * Dd + n0 + tx];
    __syncthreads();
    #pragma unroll
    for (int rr = 0; rr < 4; ++rr)
        Wt[(size_t)(n0 + ty + rr*8) * Dd + k0 + tx] =
            __float2bfloat16(t[tx][ty + rr*8]);
}

// ---------------------------------------------------------------------------
// m97-style bf16 MFMA GEMM: C = A(M,K) @ Bt(N,K)^T + bias
// 128x128 block tile, BK=32, 256 thr (4 waves, 2x2 of 64x64), 16 MFMA/K-iter.
// MODE 0: QKV epilogue — bf16 scatter to Q[B,H,S,hd] (x0.125), K[B,H,S,hd],
//         V^T[B,H,hd,S]; block-uniform sel = col0>>10.
// MODE 1: O epilogue — fp32 [M,N] with bias + ReLU.
// ---------------------------------------------------------------------------
template<int MODE>
__global__ __launch_bounds__(256)
void gemm_mfma(const __hip_bfloat16* __restrict__ A,
               const __hip_bfloat16* __restrict__ Bt,
               const float* __restrict__ b0, const float* __restrict__ b1,
               const float* __restrict__ b2,
               __hip_bfloat16* __restrict__ Qh, __hip_bfloat16* __restrict__ Kh,
               __hip_bfloat16* __restrict__ Vt, float* __restrict__ Ro,
               int M, int N, int K)
{
    __shared__ __hip_bfloat16 As[128 * 32];
    __shared__ __hip_bfloat16 Bs[128 * 32];

    const int tid  = threadIdx.x;
    const int wave = tid >> 6;
    const int lane = tid & 63;
    const int llo  = lane & 15;
    const int lhi  = lane >> 4;
    const int wm   = wave & 1;      // wave row (0/1)
    const int wn   = wave >> 1;     // wave col (0/1)
    const int row0 = blockIdx.y * 128;
    const int col0 = blockIdx.x * 128;

    f4_t acc[4][4] = {};

    for (int k0 = 0; k0 < K; k0 += 32) {
        // stage A,B tiles [128][32] bf16 via global_load_lds (512 granules ea)
        #pragma unroll
        for (int p = 0; p < 2; ++p) {
            const int g   = p * 256 + wave * 64 + lane;   // granule id
            const int r   = g >> 2;
            const int kc  = (g & 3) * 8;
            const int lof = (p * 256 + wave * 64) * 16;   // wave-uniform
            gl2lds16(&A[(size_t)(row0 + r) * K + k0 + kc], (char*)As + lof);
            gl2lds16(&Bt[(size_t)(col0 + r) * K + k0 + kc], (char*)Bs + lof);
        }
        __syncthreads();

        bf8_t a[4], b[4];
        #pragma unroll
        for (int i = 0; i < 4; ++i)
            a[i] = *(const bf8_t*)&As[(wm*64 + i*16 + llo) * 32 + lhi*8];
        #pragma unroll
        for (int j = 0; j < 4; ++j)
            b[j] = *(const bf8_t*)&Bs[(wn*64 + j*16 + llo) * 32 + lhi*8];
        #pragma unroll
        for (int i = 0; i < 4; ++i)
            #pragma unroll
            for (int j = 0; j < 4; ++j)
                acc[i][j] = __builtin_amdgcn_mfma_f32_16x16x32_bf16(
                    a[i], b[j], acc[i][j], 0, 0, 0);
        __syncthreads();
    }

    // ---- epilogue ----
    if (MODE == 0) {
        const int sel   = col0 >> 10;            // 0=Q 1=K 2=V (block-uniform)
        const int cbase = col0 & 1023;
        const float scale = (sel == 0) ? 0.125f : 1.0f;
        const float* bp = (sel == 0) ? b0 : (sel == 1) ? b1 : b2;
        __hip_bfloat16* outQK = (sel == 0) ? Qh : Kh;
        #pragma unroll
        for (int i = 0; i < 4; ++i) {
            #pragma unroll
            for (int r = 0; r < 4; ++r) {
                const int m  = row0 + wm*64 + i*16 + lhi*4 + r;
                const int b_ = m >> 11, s_ = m & (Ss - 1);
                #pragma unroll
                for (int j = 0; j < 4; ++j) {
                    const int col = cbase + wn*64 + j*16 + llo;
                    const int h_  = col >> 6, e_ = col & 63;
                    const float v = (acc[i][j][r] + bp[col]) * scale;
                    const __hip_bfloat16 hv = __float2bfloat16(v);
                    if (sel < 2)
                        outQK[((size_t)(b_*Hh + h_)*Ss + s_)*HD + e_] = hv;
                    else
                        Vt[((size_t)(b_*Hh + h_)*HD + e_)*Ss + s_] = hv;
                }
            }
        }
    } else {
        #pragma unroll
        for (int i = 0; i < 4; ++i) {
            #pragma unroll
            for (int r = 0; r < 4; ++r) {
                const int m = row0 + wm*64 + i*16 + lhi*4 + r;
                #pragma unroll
                for (int j = 0; j < 4; ++j) {
                    const int col = col0 + wn*64 + j*16 + llo;
                    Ro[(size_t)m * N + col] =
                        fmaxf(acc[i][j][r] + b0[col], 0.0f);
                }
            }
        }
    }
}

// ---------------------------------------------------------------------------
// MFMA flash attention (unchanged structure), now writes bf16 [B,S,D].
// ---------------------------------------------------------------------------
__device__ __forceinline__ float redmax16(float v) {
    v = fmaxf(v, __shfl_xor(v, 1));
    v = fmaxf(v, __shfl_xor(v, 2));
    v = fmaxf(v, __shfl_xor(v, 4));
    v = fmaxf(v, __shfl_xor(v, 8));
    return v;
}
__device__ __forceinline__ float redsum16(float v) {
    v += __shfl_xor(v, 1);
    v += __shfl_xor(v, 2);
    v += __shfl_xor(v, 4);
    v += __shfl_xor(v, 8);
    return v;
}

__global__ __launch_bounds__(256, 2)
void attn_mfma(const __hip_bfloat16* __restrict__ Qh,
               const __hip_bfloat16* __restrict__ Kh,
               const __hip_bfloat16* __restrict__ Vt,
               __hip_bfloat16* __restrict__ Ah)
{
    const int b    = blockIdx.z;
    const int h    = blockIdx.y;
    const int wave = threadIdx.x >> 6;
    const int lane = threadIdx.x & 63;
    const int llo  = lane & 15;
    const int lhi  = lane >> 4;
    const int qb   = blockIdx.x * 128 + wave * 32;

    const size_t base = ((size_t)(b*Hh + h)) * Ss * HD;
    const __hip_bfloat16* Kp = Kh + base;
    const __hip_bfloat16* Vp = Vt + base;

    __shared__ __hip_bfloat16 Pl[4][32*64];
    __hip_bfloat16* Pw = &Pl[wave][0];

    bf8_t qf[2][2];
    #pragma unroll
    for (int s = 0; s < 2; ++s)
        #pragma unroll
        for (int d = 0; d < 2; ++d)
            qf[s][d] = *(const bf8_t*)&Qh[base + (size_t)(qb + 16*s + llo)*HD + 32*d + lhi*8];

    f4_t o_[2][4];
    float mrow[2][4], lrow[2][4];
    #pragma unroll
    for (int s = 0; s < 2; ++s) {
        #pragma unroll
        for (int n = 0; n < 4; ++n) o_[s][n] = (f4_t){0.f,0.f,0.f,0.f};
        #pragma unroll
        for (int r = 0; r < 4; ++r) { mrow[s][r] = -1e30f; lrow[s][r] = 0.f; }
    }

    const f4_t zf = {0.f,0.f,0.f,0.f};
    const int llo7 = llo & 7;
    const int llo8 = llo >> 3;

    for (int k0 = 0; k0 < Ss; k0 += 64) {
        f4_t sacc[2][4];
        #pragma unroll
        for (int ks = 0; ks < 4; ++ks) {
            const __hip_bfloat16* kr = &Kp[(size_t)(k0 + 16*ks + llo)*HD + lhi*8];
            const bf8_t kf0 = *(const bf8_t*)kr;
            const bf8_t kf1 = *(const bf8_t*)(kr + 32);
            #pragma unroll
            for (int s = 0; s < 2; ++s) {
                sacc[s][ks] = __builtin_amdgcn_mfma_f32_16x16x32_bf16(qf[s][0], kf0, zf, 0, 0, 0);
                sacc[s][ks] = __builtin_amdgcn_mfma_f32_16x16x32_bf16(qf[s][1], kf1, sacc[s][ks], 0, 0, 0);
            }
        }

        float alpha[2][4];
        #pragma unroll
        for (int s = 0; s < 2; ++s) {
            #pragma unroll
            for (int r = 0; r < 4; ++r) {
                const float s0 = sacc[s][0][r], s1 = sacc[s][1][r];
                const float s2 = sacc[s][2][r], s3 = sacc[s][3][r];
                float mx = fmaxf(fmaxf(s0, s1), fmaxf(s2, s3));
                mx = redmax16(mx);
                const float nm = fmaxf(mrow[s][r], mx);
                alpha[s][r] = exp2f((mrow[s][r] - nm) * LOG2E);
                mrow[s][r] = nm;
                const float nb = -nm * LOG2E;
                const float p0 = exp2f(fmaf(s0, LOG2E, nb));
                const float p1 = exp2f(fmaf(s1, LOG2E, nb));
                const float p2 = exp2f(fmaf(s2, LOG2E, nb));
                const float p3 = exp2f(fmaf(s3, LOG2E, nb));
                const float sm = redsum16(p0 + p1 + p2 + p3);
                lrow[s][r] = fmaf(lrow[s][r], alpha[s][r], sm);
                const int q   = 16*s + 4*lhi + r;
                const int q7  = q & 7;
                const int ro  = q*64 + llo7;
                Pw[ro + (((llo8 + 0) ^ q7) << 3)] = __float2bfloat16(p0);
                Pw[ro + (((llo8 + 2) ^ q7) << 3)] = __float2bfloat16(p1);
                Pw[ro + (((llo8 + 4) ^ q7) << 3)] = __float2bfloat16(p2);
                Pw[ro + (((llo8 + 6) ^ q7) << 3)] = __float2bfloat16(p3);
            }
        }
        asm volatile("s_waitcnt lgkmcnt(0)" ::: "memory");

        #pragma unroll
        for (int s = 0; s < 2; ++s)
            #pragma unroll
            for (int n = 0; n < 4; ++n)
                #pragma unroll
                for (int r = 0; r < 4; ++r)
                    o_[s][n][r] *= alpha[s][r];

        #pragma unroll
        for (int d = 0; d < 2; ++d) {
            bf8_t pf[2];
            #pragma unroll
            for (int s = 0; s < 2; ++s) {
                const int q = 16*s + llo;
                pf[s] = *(const bf8_t*)&Pw[q*64 + ((((d<<2) + lhi) ^ (q & 7)) << 3)];
            }
            #pragma unroll
            for (int n = 0; n < 4; ++n) {
                const bf8_t vf = *(const bf8_t*)&Vp[(size_t)(llo + 16*n)*Ss + k0 + 32*d + lhi*8];
                #pragma unroll
                for (int s = 0; s < 2; ++s)
                    o_[s][n] = __builtin_amdgcn_mfma_f32_16x16x32_bf16(pf[s], vf, o_[s][n], 0, 0, 0);
            }
        }
        asm volatile("" ::: "memory");
    }

    #pragma unroll
    for (int s = 0; s < 2; ++s) {
        #pragma unroll
        for (int r = 0; r < 4; ++r) {
            const float inv = 1.0f / lrow[s][r];
            const int q = qb + 16*s + 4*lhi + r;
            __hip_bfloat16* orow = &Ah[((size_t)(b*Ss) + q)*Dd + h*HD + llo];
            #pragma unroll
            for (int n = 0; n < 4; ++n)
                orow[16*n] = __float2bfloat16(o_[s][n][r] * inv);
        }
    }
}

// ---------------------------------------------------------------------------
// LayerNorm over last dim (1024), no affine. One block per row.
// ---------------------------------------------------------------------------
__global__ __launch_bounds__(256)
void layernorm(const float* __restrict__ X, float* __restrict__ out)
{
    const int row = blockIdx.x;
    const float4 v = ((const float4*)(X + (size_t)row*Dd))[threadIdx.x];
    float s  = v.x + v.y + v.z + v.w;
    float ss = v.x*v.x + v.y*v.y + v.z*v.z + v.w*v.w;
    #pragma unroll
    for (int off = 32; off > 0; off >>= 1) {
        s  += __shfl_down(s,  off);
        ss += __shfl_down(ss, off);
    }
    __shared__ float rs[4], rss[4];
    const int wid = threadIdx.x >> 6, lid = threadIdx.x & 63;
    if (lid == 0) { rs[wid] = s; rss[wid] = ss; }
    __syncthreads();
    s  = rs[0] + rs[1] + rs[2] + rs[3];
    ss = rss[0] + rss[1] + rss[2] + rss[3];
    const float mean = s * (1.0f / Dd);
    const float var  = ss * (1.0f / Dd) - mean * mean;
    const float rstd = rsqrtf(var + 1e-5f);
    float4 o;
    o.x = (v.x - mean) * rstd;
    o.y = (v.y - mean) * rstd;
    o.z = (v.z - mean) * rstd;
    o.w = (v.w - mean) * rstd;
    ((float4*)(out + (size_t)row*Dd))[threadIdx.x] = o;
}

// ---------------------------------------------------------------------------
extern "C" void kernel_launch(void* const* d_in, const int* in_sizes, int n_in,
                              void* d_out, int out_size, void* d_ws, size_t ws_size,
                              hipStream_t stream)
{
    const float* x  = (const float*)d_in[0];
    const float* Wq = (const float*)d_in[1];
    const float* bq = (const float*)d_in[2];
    const float* Wk = (const float*)d_in[3];
    const float* bk = (const float*)d_in[4];
    const float* Wv = (const float*)d_in[5];
    const float* bv = (const float*)d_in[6];
    const float* Wo = (const float*)d_in[7];
    const float* bo = (const float*)d_in[8];
    float* out = (float*)d_out;

    // ws (bf16 elems unless noted):
    // Xh[4096*1024] 8MB | Wqkvt[3072*1024] 6MB | Wot[1024*1024] 2MB |
    // Qh 8MB | Kh 8MB | Vt 8MB | Ah 8MB          (Rb fp32 16MB reuses Qh+Kh)
    __hip_bfloat16* Xh    = (__hip_bfloat16*)d_ws;
    __hip_bfloat16* Wqkvt = Xh    + (size_t)Mm*Dd;
    __hip_bfloat16* Wot   = Wqkvt + (size_t)3*Dd*Dd;
    __hip_bfloat16* Qh    = Wot   + (size_t)Dd*Dd;
    __hip_bfloat16* Kh    = Qh    + (size_t)Mm*Dd;
    __hip_bfloat16* Vt    = Kh    + (size_t)Mm*Dd;
    __hip_bfloat16* Ah    = Vt    + (size_t)Mm*Dd;
    float*          Rb    = (float*)Qh;   // Q/K dead after attention

    const dim3 blk(256);
    cast_x<<<dim3((Mm*Dd)/(256*8)), blk, 0, stream>>>(x, Xh);
    tcast<<<dim3(32, 32), blk, 0, stream>>>(Wq, Wqkvt);
    tcast<<<dim3(32, 32), blk, 0, stream>>>(Wk, Wqkvt + (size_t)Dd*Dd);
    tcast<<<dim3(32, 32), blk, 0, stream>>>(Wv, Wqkvt + (size_t)2*Dd*Dd);
    tcast<<<dim3(32, 32), blk, 0, stream>>>(Wo, Wot);

    gemm_mfma<0><<<dim3(3*Dd/128, Mm/128), blk, 0, stream>>>(
        Xh, Wqkvt, bq, bk, bv, Qh, Kh, Vt, nullptr, Mm, 3*Dd, Dd);
    attn_mfma<<<dim3(Ss/128, Hh, Bb), blk, 0, stream>>>(Qh, Kh, Vt, Ah);
    gemm_mfma<1><<<dim3(Dd/128, Mm/128), blk, 0, stream>>>(
        Ah, Wot, bo, nullptr, nullptr, nullptr, nullptr, nullptr, Rb, Mm, Dd, Dd);
    layernorm<<<dim3(Mm), blk, 0, stream>>>(Rb, out);
}